// Round 14
// baseline (253.845 us; speedup 1.0000x reference)
//
#include <hip/hip_runtime.h>
#include <math.h>

// GCN 2-layer forward on MI355X.
// Lessons r2-r6: (a) random 4B global stores/ATOMICS => bad; (b) coarse
// buckets => re-read; (c) LDS-accumulator agg latency-serial; (d) wave-per-
// node CSR gather agg fast. Bucket partition -> per-bucket LDS counting
// sort -> CSR gather aggs; log_softmax in agg2.
// r9: bf16 intermediates. r12: 4x8 reg tile gemm1. r13: bucket||gemm1
// fusion. r15: sort-epilogue m1b prescale. r16/r18: 202us best.
// Bucket-phase bracket: r15 (more blocks) X, r17 (more waves) X, r19
// (LDS counting sort: WRITE 45->28MB as predicted but time 62->77 --
// LDS-atomic bound, NOT write-amp bound) X. r16 form is the optimum.
// r20: fuse gemm2 into agg1 epilogue: after the xor-reduce each lane
// holds 8 channels of a1; 64 shfl-broadcasts + 64 FMA vs LDS W2 give
// lane c its m2 channel; pack pairs, write m2b. Deletes gemm2 dispatch
// + the 51MB a1 round-trip. m2b moved off m1b (agg1 reads m1b live).

#define NN 100000
#define NE 3200000
#define NBUK 391            // ceil(NN/256); bucket b covers cols [b*256 ...)
#define BCAP 8704           // mean 8184, sd ~90; +5.7 sigma slack
#define EPB 16384           // edges per bucket block
#define NBB ((NE + EPB - 1) / EPB)   // 196 bucket blocks
#define NGB 782                      // gemm1 blocks (782*128 >= NN)

typedef __attribute__((ext_vector_type(2))) float f32x2;

// ---------------- bf16 helpers ----------------

__device__ __forceinline__ unsigned bf16rne(float x) {
  unsigned u = __float_as_uint(x);
  return (u + 0x7fffu + ((u >> 16) & 1u)) >> 16;
}
__device__ __forceinline__ unsigned pack2(float lo, float hi) {
  return bf16rne(lo) | (bf16rne(hi) << 16);
}

// ---------------- packed fp32 FMA (VOP3P) ----------------

__device__ __forceinline__ void pkfma(f32x2& a, f32x2 v, f32x2 f) {
  asm("v_pk_fma_f32 %0, %1, %2, %0" : "+v"(a) : "v"(v), "v"(f));
}

#define ACCP(vv, fp) {                                                      \
  f32x2 t0, t1, t2, t3;                                                     \
  t0.x = __uint_as_float((vv).x << 16);                                     \
  t0.y = __uint_as_float((vv).x & 0xffff0000u);                             \
  t1.x = __uint_as_float((vv).y << 16);                                     \
  t1.y = __uint_as_float((vv).y & 0xffff0000u);                             \
  t2.x = __uint_as_float((vv).z << 16);                                     \
  t2.y = __uint_as_float((vv).z & 0xffff0000u);                             \
  t3.x = __uint_as_float((vv).w << 16);                                     \
  t3.y = __uint_as_float((vv).w & 0xffff0000u);                             \
  pkfma(acc2[0], t0, fp);                                                   \
  pkfma(acc2[1], t1, fp);                                                   \
  pkfma(acc2[2], t2, fp);                                                   \
  pkfma(acc2[3], t3, fp);                                                   \
}

__device__ __forceinline__ float shfl1(float v, int src) {
  return __shfl(v, src & 63, 64);
}

// ---------------- fused: bucket partition (blocks 0..NBB-1) ----------------
// ----------------        + layer-1 GEMM  (blocks NBB..NBB+781) -------------
// 256 threads (r16 optimum). gemm1: 128-row tiles, 4x8 reg tile, output
// UNSCALED bf16 (prescaled later by k_sort epilogue).

__global__ __launch_bounds__(256) void k_bucket_gemm1(const int* __restrict__ ei,
                                                      int* __restrict__ tail,
                                                      unsigned* __restrict__ bucket,
                                                      const float* __restrict__ x,
                                                      const float* __restrict__ W1,
                                                      unsigned* __restrict__ m1b) {
  __shared__ float smem[128 * 64 + 16 * 132];   // 41216 B (both roles)
  const int tid = threadIdx.x;
  const int bx = blockIdx.x;

  if (bx < NBB) {
    // ---------- bucket partition (r16 form: direct global scatter) ----------
    int* hist  = (int*)smem;            // [NBUK]
    int* wbase = hist + NBUK;
    int* loc   = wbase + NBUK;
    const int beg = bx * EPB;
    const int end = min(beg + EPB, NE);
    const int* col = ei + NE;
    for (int b = tid; b < NBUK; b += 256) { hist[b] = 0; loc[b] = 0; }
    __syncthreads();
    for (int e = beg + tid * 4; e < end; e += 1024) {
      int4 c4 = *(const int4*)(col + e);
      atomicAdd(&hist[c4.x >> 8], 1);
      atomicAdd(&hist[c4.y >> 8], 1);
      atomicAdd(&hist[c4.z >> 8], 1);
      atomicAdd(&hist[c4.w >> 8], 1);
    }
    __syncthreads();
    for (int b = tid; b < NBUK; b += 256)
      wbase[b] = atomicAdd(&tail[b], hist[b]);   // contiguous block-private run
    __syncthreads();
    for (int e = beg + tid * 4; e < end; e += 1024) {
      int4 c4 = *(const int4*)(col + e);         // L2-hot re-read
      int4 r4 = *(const int4*)(ei + e);
      {
        int b = c4.x >> 8;
        unsigned pos = (unsigned)(wbase[b] + atomicAdd(&loc[b], 1));
        if (pos < BCAP) bucket[(size_t)b * BCAP + pos] = ((unsigned)r4.x << 8) | (unsigned)(c4.x & 255);
      }
      {
        int b = c4.y >> 8;
        unsigned pos = (unsigned)(wbase[b] + atomicAdd(&loc[b], 1));
        if (pos < BCAP) bucket[(size_t)b * BCAP + pos] = ((unsigned)r4.y << 8) | (unsigned)(c4.y & 255);
      }
      {
        int b = c4.z >> 8;
        unsigned pos = (unsigned)(wbase[b] + atomicAdd(&loc[b], 1));
        if (pos < BCAP) bucket[(size_t)b * BCAP + pos] = ((unsigned)r4.z << 8) | (unsigned)(c4.z & 255);
      }
      {
        int b = c4.w >> 8;
        unsigned pos = (unsigned)(wbase[b] + atomicAdd(&loc[b], 1));
        if (pos < BCAP) bucket[(size_t)b * BCAP + pos] = ((unsigned)r4.w << 8) | (unsigned)(c4.w & 255);
      }
    }
    return;
  }

  // ---------- layer 1 GEMM: m1b = bf16(x @ W1), unscaled ----------
  float* ws = smem;                    // 32 KB, [k][c]
  float* xt = smem + 128 * 64;         // 8.25 KB, [k in slice][row pad 132]
  const int row0 = (bx - NBB) * 128;   // 782 blocks
  {
    const float4* __restrict__ w4 = (const float4*)W1;
    float4* __restrict__ s4 = (float4*)ws;
    for (int i = tid; i < 128 * 16; i += 256) s4[i] = w4[i];
  }
  const int cg = tid & 7;             // channels 8cg..8cg+7
  const int rg = tid >> 3;            // 0..31 -> rows 4rg..4rg+3
  const int srow = tid & 127;         // staging row
  const int skh = tid >> 7;           // staging k-octet (0/1)
  float acc[4][8];
  #pragma unroll
  for (int i = 0; i < 4; ++i)
    #pragma unroll
    for (int j = 0; j < 8; ++j) acc[i][j] = 0.f;
  const float4* __restrict__ xt4 = (const float4*)xt;
  const float4* __restrict__ ws4 = (const float4*)ws;
  for (int ks = 0; ks < 8; ++ks) {
    __syncthreads();
    {   // stage 128 rows x 16 k, transposed; 16B granule loads, L2-hot
      int grow = row0 + srow; if (grow > NN - 1) grow = NN - 1;
      const float* xp = x + (size_t)grow * 128 + ks * 16 + skh * 8;
      float4 va = *(const float4*)xp;
      float4 vb = *(const float4*)(xp + 4);
      const int kb = skh * 8;
      xt[(kb + 0) * 132 + srow] = va.x;
      xt[(kb + 1) * 132 + srow] = va.y;
      xt[(kb + 2) * 132 + srow] = va.z;
      xt[(kb + 3) * 132 + srow] = va.w;
      xt[(kb + 4) * 132 + srow] = vb.x;
      xt[(kb + 5) * 132 + srow] = vb.y;
      xt[(kb + 6) * 132 + srow] = vb.z;
      xt[(kb + 7) * 132 + srow] = vb.w;
    }
    __syncthreads();
    #pragma unroll 4
    for (int kk = 0; kk < 16; ++kk) {
      const int k = ks * 16 + kk;
      float4 xv = xt4[kk * 33 + rg];
      float4 wa = ws4[k * 16 + cg * 2];
      float4 wb = ws4[k * 16 + cg * 2 + 1];
      float xr[4] = {xv.x, xv.y, xv.z, xv.w};
      float wc[8] = {wa.x, wa.y, wa.z, wa.w, wb.x, wb.y, wb.z, wb.w};
      #pragma unroll
      for (int i = 0; i < 4; ++i)
        #pragma unroll
        for (int j = 0; j < 8; ++j)
          acc[i][j] = fmaf(xr[i], wc[j], acc[i][j]);
    }
  }
  #pragma unroll
  for (int i = 0; i < 4; ++i) {
    const int row = row0 + rg * 4 + i;
    if (row < NN) {
      uint4 o;
      o.x = pack2(acc[i][0], acc[i][1]);
      o.y = pack2(acc[i][2], acc[i][3]);
      o.z = pack2(acc[i][4], acc[i][5]);
      o.w = pack2(acc[i][6], acc[i][7]);
      ((uint4*)m1b)[row * 8 + cg] = o;   // ch 8cg..8cg+7
    }
  }
}

// ---------------- per-bucket LDS counting sort -> CSR + offsets + dinv ------
// seg0 computed in-block (scan of min(tail[0..b),BCAP), L2-hot). Epilogue:
// scale this bucket's 256 m1b rows in place by their dinv.

__global__ __launch_bounds__(256) void k_sort(const unsigned* __restrict__ bucket,
                                              const int* __restrict__ tail,
                                              int* __restrict__ csr_src,
                                              int* __restrict__ offsets,
                                              float* __restrict__ dinv,
                                              unsigned* __restrict__ m1b) {
  __shared__ int h[256], base_[256], loc[256];
  __shared__ float dv[256];
  __shared__ int sorted[BCAP];              // 34.8 KB
  __shared__ int wsum[4];
  __shared__ int seg0_s;
  const int b = blockIdx.x;
  const int lo = b << 8;
  const int nc = min(256, NN - lo);
  const int n = min(tail[b], BCAP);
  const unsigned* __restrict__ bk = bucket + (size_t)b * BCAP;
  const int tid = threadIdx.x, lane = tid & 63, wid = tid >> 6;
  h[tid] = 0; loc[tid] = 0;
  if (wid == 0) {
    int local = 0;
    const int lim = (b < NBUK) ? b : NBUK;     // sum over j < b
    for (int j = lane; j < lim; j += 64) local += min(tail[j], BCAP);
    #pragma unroll
    for (int d = 32; d > 0; d >>= 1) local += __shfl_xor(local, d, 64);
    if (lane == 0) seg0_s = local;
  }
  __syncthreads();
  const int seg0 = seg0_s;
  int i = tid * 4;
  for (; i + 3 < n; i += 1024) {
    uint4 v = *(const uint4*)(bk + i);
    atomicAdd(&h[v.x & 255u], 1);
    atomicAdd(&h[v.y & 255u], 1);
    atomicAdd(&h[v.z & 255u], 1);
    atomicAdd(&h[v.w & 255u], 1);
  }
  for (; i < n; ++i) atomicAdd(&h[bk[i] & 255u], 1);
  __syncthreads();
  {  // exclusive scan of h[0..255]
    int v = h[tid];
    int s = v;
    #pragma unroll
    for (int d = 1; d < 64; d <<= 1) { int t = __shfl_up(s, d, 64); if (lane >= d) s += t; }
    if (lane == 63) wsum[wid] = s;
    __syncthreads();
    int wpre = 0;
    #pragma unroll
    for (int w = 0; w < 4; ++w) if (w < wid) wpre += wsum[w];
    int excl = wpre + s - v;
    base_[tid] = excl;
    const float dval = rsqrtf((float)(v + 1));     // +1 = self-loop
    dv[tid] = dval;
    if (tid < nc) {
      dinv[lo + tid] = dval;
      offsets[lo + tid] = seg0 + excl;
    }
  }
  if (b == NBUK - 1 && tid == 0) offsets[NN] = seg0 + n;
  __syncthreads();
  i = tid * 4;
  for (; i + 3 < n; i += 1024) {
    uint4 v = *(const uint4*)(bk + i);
    { int c = v.x & 255u; sorted[base_[c] + atomicAdd(&loc[c], 1)] = (int)(v.x >> 8); }
    { int c = v.y & 255u; sorted[base_[c] + atomicAdd(&loc[c], 1)] = (int)(v.y >> 8); }
    { int c = v.z & 255u; sorted[base_[c] + atomicAdd(&loc[c], 1)] = (int)(v.z >> 8); }
    { int c = v.w & 255u; sorted[base_[c] + atomicAdd(&loc[c], 1)] = (int)(v.w >> 8); }
  }
  for (; i < n; ++i) {
    unsigned ent = bk[i];
    int c = ent & 255u;
    sorted[base_[c] + atomicAdd(&loc[c], 1)] = (int)(ent >> 8);
  }
  __syncthreads();
  for (int t = tid; t < n; t += 256) csr_src[seg0 + t] = sorted[t];   // coalesced
  // ---- scale m1b rows of this bucket's nodes (coalesced, 8 lanes/row) ----
  {
    const int q = tid & 7;
    uint4* __restrict__ m1rw = (uint4*)m1b;
    for (int r = tid >> 3; r < nc; r += 32) {
      const float d = dv[r];
      uint4 v = m1rw[(size_t)(lo + r) * 8 + q];
      v.x = pack2(__uint_as_float(v.x << 16) * d, __uint_as_float(v.x & 0xffff0000u) * d);
      v.y = pack2(__uint_as_float(v.y << 16) * d, __uint_as_float(v.y & 0xffff0000u) * d);
      v.z = pack2(__uint_as_float(v.z << 16) * d, __uint_as_float(v.z & 0xffff0000u) * d);
      v.w = pack2(__uint_as_float(v.w << 16) * d, __uint_as_float(v.w & 0xffff0000u) * d);
      m1rw[(size_t)(lo + r) * 8 + q] = v;
    }
  }
}

// ---------------- layer 1 aggregation + FUSED layer 2 GEMM ------------------
// Gather loop unchanged (pre-scaled bf16 rows, mask 1/0, pkfma). After the
// xor-reduce every lane holds channels 8q..8q+7 of the a1 row; the 64->40
// GEMM runs in-register: 64 shfl broadcasts x 64 FMA vs LDS-staged W2;
// lane c<40 owns m2 channel c; even lanes pack pairs and write m2b.

__global__ __launch_bounds__(256) void k_agg1(const unsigned* __restrict__ m1b,
                                              const int* __restrict__ offsets,
                                              const int* __restrict__ csr_src,
                                              const float* __restrict__ dinv,
                                              const float* __restrict__ b1,
                                              const float* __restrict__ W2,
                                              unsigned* __restrict__ m2b) {
  __shared__ float ws2[64 * 40];   // 10 KB
  const int tid = threadIdx.x;
  for (int i = tid; i < 64 * 40; i += 256) ws2[i] = W2[i];
  __syncthreads();
  const int node = blockIdx.x * 4 + (tid >> 6);
  const int lane = tid & 63;
  const int e = lane >> 3;
  const int q = lane & 7;
  const uint4* __restrict__ m1v = (const uint4*)m1b;
  const int beg = offsets[node], end = offsets[node + 1];
  f32x2 acc2[4];
  #pragma unroll
  for (int j = 0; j < 4; ++j) { acc2[j].x = 0.f; acc2[j].y = 0.f; }
  for (int p = beg; p < end; p += 32) {
    const int i0 = p + e, i1 = p + 8 + e, i2 = p + 16 + e, i3 = p + 24 + e;
    const int s0 = csr_src[i0 < end ? i0 : beg];
    const int s1 = csr_src[i1 < end ? i1 : beg];
    const int s2 = csr_src[i2 < end ? i2 : beg];
    const int s3 = csr_src[i3 < end ? i3 : beg];
    f32x2 f0; f0.x = f0.y = (i0 < end) ? 1.f : 0.f;
    f32x2 f1; f1.x = f1.y = (i1 < end) ? 1.f : 0.f;
    f32x2 f2; f2.x = f2.y = (i2 < end) ? 1.f : 0.f;
    f32x2 f3; f3.x = f3.y = (i3 < end) ? 1.f : 0.f;
    uint4 v0 = m1v[s0 * 8 + q];
    uint4 v1 = m1v[s1 * 8 + q];
    uint4 v2 = m1v[s2 * 8 + q];
    uint4 v3 = m1v[s3 * 8 + q];
    ACCP(v0, f0);
    ACCP(v1, f1);
    ACCP(v2, f2);
    ACCP(v3, f3);
  }
  float acc[8];
  acc[0] = acc2[0].x; acc[1] = acc2[0].y; acc[2] = acc2[1].x; acc[3] = acc2[1].y;
  acc[4] = acc2[2].x; acc[5] = acc2[2].y; acc[6] = acc2[3].x; acc[7] = acc2[3].y;
  // reduce the 8 edge slots; afterwards ALL lanes hold chunk q's sums
  #pragma unroll
  for (int j = 0; j < 8; ++j) {
    acc[j] += __shfl_xor(acc[j], 8, 64);
    acc[j] += __shfl_xor(acc[j], 16, 64);
    acc[j] += __shfl_xor(acc[j], 32, 64);
  }
  // a1 row channels 8q..8q+7 in-register (all lanes)
  const float d = dinv[node];
  float av[8];
  {
    uint4 sv = m1v[node * 8 + q];     // self-loop row (pre-scaled); broadcast
    float4 bb0 = ((const float4*)b1)[q * 2];
    float4 bb1 = ((const float4*)b1)[q * 2 + 1];
    av[0] = (acc[0] + __uint_as_float(sv.x << 16)) * d + bb0.x;
    av[1] = (acc[1] + __uint_as_float(sv.x & 0xffff0000u)) * d + bb0.y;
    av[2] = (acc[2] + __uint_as_float(sv.y << 16)) * d + bb0.z;
    av[3] = (acc[3] + __uint_as_float(sv.y & 0xffff0000u)) * d + bb0.w;
    av[4] = (acc[4] + __uint_as_float(sv.z << 16)) * d + bb1.x;
    av[5] = (acc[5] + __uint_as_float(sv.z & 0xffff0000u)) * d + bb1.y;
    av[6] = (acc[6] + __uint_as_float(sv.w << 16)) * d + bb1.z;
    av[7] = (acc[7] + __uint_as_float(sv.w & 0xffff0000u)) * d + bb1.w;
  }
  // in-register 64->40 GEMM: lane c = output channel
  const int c = lane;
  const int cc = (c < 40) ? c : 0;
  float dot = 0.f;
  #pragma unroll
  for (int k = 0; k < 64; ++k) {
    float contrib = shfl1(av[k & 7], k >> 3);   // channel k of the a1 row
    dot = fmaf(contrib, ws2[k * 40 + cc], dot);
  }
  // m2 = dinv * (a1 @ W2); pack channel pairs on even lanes
  float hi = shfl1(dot, lane + 1);
  if (c < 40 && !(c & 1)) {
    m2b[node * 20 + (c >> 1)] = pack2(dot * d, hi * d);
  }
}

// ---------------- layer 2 aggregation + bias + log_softmax ------------------

__global__ __launch_bounds__(256) void k_agg2(const unsigned* __restrict__ m2b,
                                              const int* __restrict__ offsets,
                                              const int* __restrict__ csr_src,
                                              const float* __restrict__ dinv,
                                              const float* __restrict__ b2,
                                              float* __restrict__ out) {
  const int node = blockIdx.x * 4 + (threadIdx.x >> 6);
  const int lane = threadIdx.x & 63;
  const bool act = lane < 60;
  const int e = act ? (lane / 5) : 0;
  const int q = act ? (lane - e * 5) : 0;
  const uint4* __restrict__ m2v = (const uint4*)m2b;
  const int beg = offsets[node], end = offsets[node + 1];
  f32x2 acc2[4];
  #pragma unroll
  for (int j = 0; j < 4; ++j) { acc2[j].x = 0.f; acc2[j].y = 0.f; }
  for (int p = beg; p < end; p += 48) {
    const int i0 = p + e, i1 = p + 12 + e, i2 = p + 24 + e, i3 = p + 36 + e;
    const int s0 = csr_src[i0 < end ? i0 : beg];
    const int s1 = csr_src[i1 < end ? i1 : beg];
    const int s2 = csr_src[i2 < end ? i2 : beg];
    const int s3 = csr_src[i3 < end ? i3 : beg];
    f32x2 f0; f0.x = f0.y = (act && i0 < end) ? 1.f : 0.f;
    f32x2 f1; f1.x = f1.y = (act && i1 < end) ? 1.f : 0.f;
    f32x2 f2; f2.x = f2.y = (act && i2 < end) ? 1.f : 0.f;
    f32x2 f3; f3.x = f3.y = (act && i3 < end) ? 1.f : 0.f;
    uint4 v0 = m2v[s0 * 5 + q];
    uint4 v1 = m2v[s1 * 5 + q];
    uint4 v2 = m2v[s2 * 5 + q];
    uint4 v3 = m2v[s3 * 5 + q];
    ACCP(v0, f0);
    ACCP(v1, f1);
    ACCP(v2, f2);
    ACCP(v3, f3);
  }
  float acc[8];
  acc[0] = acc2[0].x; acc[1] = acc2[0].y; acc[2] = acc2[1].x; acc[3] = acc2[1].y;
  acc[4] = acc2[2].x; acc[5] = acc2[2].y; acc[6] = acc2[3].x; acc[7] = acc2[3].y;
  #pragma unroll
  for (int j = 0; j < 8; ++j) acc[j] += shfl1(acc[j], lane + 30);
  #pragma unroll
  for (int j = 0; j < 8; ++j) acc[j] += shfl1(acc[j], lane + 15);
  #pragma unroll
  for (int j = 0; j < 8; ++j) {
    float t1 = shfl1(acc[j], lane + 5);
    float t2 = shfl1(acc[j], lane + 10);
    acc[j] += t1 + t2;
  }
  const bool lead = (lane < 5);
  float r[8];
  #pragma unroll
  for (int j = 0; j < 8; ++j) r[j] = 0.f;
  if (lead) {
    uint4 sv = m2v[node * 5 + lane];   // self-loop row (q == lane here)
    const float d = dinv[node];
    float4 bb0 = ((const float4*)b2)[lane * 2];
    float4 bb1 = ((const float4*)b2)[lane * 2 + 1];
    r[0] = (acc[0] + __uint_as_float(sv.x << 16)) * d + bb0.x;
    r[1] = (acc[1] + __uint_as_float(sv.x & 0xffff0000u)) * d + bb0.y;
    r[2] = (acc[2] + __uint_as_float(sv.y << 16)) * d + bb0.z;
    r[3] = (acc[3] + __uint_as_float(sv.y & 0xffff0000u)) * d + bb0.w;
    r[4] = (acc[4] + __uint_as_float(sv.z << 16)) * d + bb1.x;
    r[5] = (acc[5] + __uint_as_float(sv.z & 0xffff0000u)) * d + bb1.y;
    r[6] = (acc[6] + __uint_as_float(sv.w << 16)) * d + bb1.z;
    r[7] = (acc[7] + __uint_as_float(sv.w & 0xffff0000u)) * d + bb1.w;
  }
  float mx = -INFINITY;
  if (lead) {
    mx = fmaxf(fmaxf(fmaxf(r[0], r[1]), fmaxf(r[2], r[3])),
               fmaxf(fmaxf(r[4], r[5]), fmaxf(r[6], r[7])));
  }
  #pragma unroll
  for (int d = 4; d > 0; d >>= 1) mx = fmaxf(mx, __shfl_xor(mx, d, 8));
  float se = 0.f;
  if (lead) {
    se = __expf(r[0] - mx) + __expf(r[1] - mx) + __expf(r[2] - mx) +
         __expf(r[3] - mx) + __expf(r[4] - mx) + __expf(r[5] - mx) +
         __expf(r[6] - mx) + __expf(r[7] - mx);
  }
  #pragma unroll
  for (int d = 4; d > 0; d >>= 1) se += __shfl_xor(se, d, 8);
  if (lead) {
    const float lse = mx + logf(se);
    float4 o0, o1;
    o0.x = r[0] - lse; o0.y = r[1] - lse; o0.z = r[2] - lse; o0.w = r[3] - lse;
    o1.x = r[4] - lse; o1.y = r[5] - lse; o1.z = r[6] - lse; o1.w = r[7] - lse;
    ((float4*)out)[node * 10 + lane * 2] = o0;
    ((float4*)out)[node * 10 + lane * 2 + 1] = o1;
  }
}

// ---------------- launch ----------------

extern "C" void kernel_launch(void* const* d_in, const int* in_sizes, int n_in,
                              void* d_out, int out_size, void* d_ws, size_t ws_size,
                              hipStream_t stream) {
  const float* x   = (const float*)d_in[0];
  const int*   ei  = (const int*)d_in[1];   // [2][NE], int32
  const float* W1  = (const float*)d_in[3];
  const float* b1  = (const float*)d_in[4];
  const float* W2  = (const float*)d_in[5];
  const float* b2  = (const float*)d_in[6];
  float*       out = (float*)d_out;

  // workspace layout (liveness-checked):
  //   tail 0..1.6K | offsets 8K..0.4M | dinv 0.5M..0.9M
  //   csr_src 1.5M..14.3M
  //   m1b 14.5M..27.3M (fused gemm1 writes; concurrent with bucket;
  //                     scaled in place by k_sort epilogue; read by agg1)
  //   bucket 27.5M..40.5M (dead after k_sort)
  //   m2b 27.5M..35.5M (overlays bucket; written by agg1 after sort)
  char* ws = (char*)d_ws;
  int*      tail    = (int*)(ws + 0);
  int*      offsets = (int*)(ws + (size_t)8 * 1024);
  float*    dinv    = (float*)(ws + (size_t)512 * 1024);
  int*      csr_src = (int*)(ws + (size_t)1536 * 1024);
  unsigned* m1b     = (unsigned*)(ws + (size_t)14848 * 1024);    // 14.5MB
  unsigned* bucket  = (unsigned*)(ws + (size_t)28160 * 1024);    // 27.5MB
  unsigned* m2b     = (unsigned*)(ws + (size_t)28160 * 1024);    // overlays bucket

  hipMemsetAsync(tail, 0, NBUK * 4, stream);
  k_bucket_gemm1<<<NBB + NGB, 256, 0, stream>>>(ei, tail, bucket, x, W1, m1b);
  k_sort<<<NBUK, 256, 0, stream>>>(bucket, tail, csr_src, offsets, dinv, m1b);
  k_agg1<<<NN / 4, 256, 0, stream>>>(m1b, offsets, csr_src, dinv, b1, W2, m2b);
  k_agg2<<<NN / 4, 256, 0, stream>>>(m2b, offsets, csr_src, dinv, b2, out);
}

// Round 15
// 202.360 us; speedup vs baseline: 1.2544x; 1.2544x over previous
//
#include <hip/hip_runtime.h>
#include <math.h>

// GCN 2-layer forward on MI355X.
// Lessons r2-r6: (a) random 4B global stores/ATOMICS => bad (r13 k_deg
// 130us; r15/r17: adding parallelism to the scatter partition in ANY form
// worsens write-amp/contention; 196x4waves local optimum); (b) coarse
// buckets => re-read; (c) LDS-accumulator agg latency-serial; (d) wave-per-
// node CSR gather agg fast; (e) r20: cross-lane shuffle chains serialize
// -- a 64-deep shfl->FMA chain tripled agg1. Bucket partition -> per-bucket
// LDS counting sort -> CSR gather aggs; log_softmax in agg2.
// r9: bf16 intermediates. r12: 4x8 reg tile + 12 waves/CU gemm1.
// r13: bucket||gemm1 fusion (gemm1 rides free). r15: sort-epilogue m1b
// prescale. r16/r18: EPB 16384 + prescale + in-sort prefix = 202us BEST.
// Bracketed: bucket (r15/r17/r19 X), gemm1 tile (r10/r11 X), agg width
// (r7/r8 saturated), agg precision (r9), gemm2 fusion (r20 X).
// r21: revert to r18 verbatim -- the measured optimum.

#define NN 100000
#define NE 3200000
#define NBUK 391            // ceil(NN/256); bucket b covers cols [b*256 ...)
#define BCAP 8704           // mean 8184, sd ~90; +5.7 sigma slack
#define EPB 16384           // edges per bucket block
#define NBB ((NE + EPB - 1) / EPB)   // 196 bucket blocks
#define NGB 782                      // gemm1 blocks (782*128 >= NN)

typedef __attribute__((ext_vector_type(2))) float f32x2;

// ---------------- bf16 helpers ----------------

__device__ __forceinline__ unsigned bf16rne(float x) {
  unsigned u = __float_as_uint(x);
  return (u + 0x7fffu + ((u >> 16) & 1u)) >> 16;
}
__device__ __forceinline__ unsigned pack2(float lo, float hi) {
  return bf16rne(lo) | (bf16rne(hi) << 16);
}

// ---------------- packed fp32 FMA (VOP3P) ----------------

__device__ __forceinline__ void pkfma(f32x2& a, f32x2 v, f32x2 f) {
  asm("v_pk_fma_f32 %0, %1, %2, %0" : "+v"(a) : "v"(v), "v"(f));
}

// acc2[4] covers 8 channels; unpack uint4 (8 bf16) and accumulate with
// weight pair fp (fp.x == fp.y).
#define ACCP(vv, fp) {                                                      \
  f32x2 t0, t1, t2, t3;                                                     \
  t0.x = __uint_as_float((vv).x << 16);                                     \
  t0.y = __uint_as_float((vv).x & 0xffff0000u);                             \
  t1.x = __uint_as_float((vv).y << 16);                                     \
  t1.y = __uint_as_float((vv).y & 0xffff0000u);                             \
  t2.x = __uint_as_float((vv).z << 16);                                     \
  t2.y = __uint_as_float((vv).z & 0xffff0000u);                             \
  t3.x = __uint_as_float((vv).w << 16);                                     \
  t3.y = __uint_as_float((vv).w & 0xffff0000u);                             \
  pkfma(acc2[0], t0, fp);                                                   \
  pkfma(acc2[1], t1, fp);                                                   \
  pkfma(acc2[2], t2, fp);                                                   \
  pkfma(acc2[3], t3, fp);                                                   \
}

// ---------------- fused: bucket partition (blocks 0..NBB-1) ----------------
// ----------------        + layer-1 GEMM  (blocks NBB..NBB+781) -------------
// 256 threads (r16 optimum). gemm1: 128-row tiles, 4x8 reg tile, output
// UNSCALED bf16 (prescaled later by k_sort epilogue).

__global__ __launch_bounds__(256) void k_bucket_gemm1(const int* __restrict__ ei,
                                                      int* __restrict__ tail,
                                                      unsigned* __restrict__ bucket,
                                                      const float* __restrict__ x,
                                                      const float* __restrict__ W1,
                                                      unsigned* __restrict__ m1b) {
  __shared__ float smem[128 * 64 + 16 * 132];   // 41216 B (both roles)
  const int tid = threadIdx.x;
  const int bx = blockIdx.x;

  if (bx < NBB) {
    // ---------- bucket partition ----------
    int* hist  = (int*)smem;            // [NBUK]
    int* wbase = hist + NBUK;
    int* loc   = wbase + NBUK;
    const int beg = bx * EPB;
    const int end = min(beg + EPB, NE);
    const int* col = ei + NE;
    for (int b = tid; b < NBUK; b += 256) { hist[b] = 0; loc[b] = 0; }
    __syncthreads();
    for (int e = beg + tid * 4; e < end; e += 1024) {
      int4 c4 = *(const int4*)(col + e);
      atomicAdd(&hist[c4.x >> 8], 1);
      atomicAdd(&hist[c4.y >> 8], 1);
      atomicAdd(&hist[c4.z >> 8], 1);
      atomicAdd(&hist[c4.w >> 8], 1);
    }
    __syncthreads();
    for (int b = tid; b < NBUK; b += 256)
      wbase[b] = atomicAdd(&tail[b], hist[b]);   // contiguous block-private run
    __syncthreads();
    for (int e = beg + tid * 4; e < end; e += 1024) {
      int4 c4 = *(const int4*)(col + e);         // L2-hot re-read
      int4 r4 = *(const int4*)(ei + e);
      {
        int b = c4.x >> 8;
        unsigned pos = (unsigned)(wbase[b] + atomicAdd(&loc[b], 1));
        if (pos < BCAP) bucket[(size_t)b * BCAP + pos] = ((unsigned)r4.x << 8) | (unsigned)(c4.x & 255);
      }
      {
        int b = c4.y >> 8;
        unsigned pos = (unsigned)(wbase[b] + atomicAdd(&loc[b], 1));
        if (pos < BCAP) bucket[(size_t)b * BCAP + pos] = ((unsigned)r4.y << 8) | (unsigned)(c4.y & 255);
      }
      {
        int b = c4.z >> 8;
        unsigned pos = (unsigned)(wbase[b] + atomicAdd(&loc[b], 1));
        if (pos < BCAP) bucket[(size_t)b * BCAP + pos] = ((unsigned)r4.z << 8) | (unsigned)(c4.z & 255);
      }
      {
        int b = c4.w >> 8;
        unsigned pos = (unsigned)(wbase[b] + atomicAdd(&loc[b], 1));
        if (pos < BCAP) bucket[(size_t)b * BCAP + pos] = ((unsigned)r4.w << 8) | (unsigned)(c4.w & 255);
      }
    }
    return;
  }

  // ---------- layer 1 GEMM: m1b = bf16(x @ W1), unscaled ----------
  float* ws = smem;                    // 32 KB, [k][c]
  float* xt = smem + 128 * 64;         // 8.25 KB, [k in slice][row pad 132]
  const int row0 = (bx - NBB) * 128;   // 782 blocks
  {
    const float4* __restrict__ w4 = (const float4*)W1;
    float4* __restrict__ s4 = (float4*)ws;
    for (int i = tid; i < 128 * 16; i += 256) s4[i] = w4[i];
  }
  const int cg = tid & 7;             // channels 8cg..8cg+7
  const int rg = tid >> 3;            // 0..31 -> rows 4rg..4rg+3
  const int srow = tid & 127;         // staging row
  const int skh = tid >> 7;           // staging k-octet (0/1)
  float acc[4][8];
  #pragma unroll
  for (int i = 0; i < 4; ++i)
    #pragma unroll
    for (int j = 0; j < 8; ++j) acc[i][j] = 0.f;
  const float4* __restrict__ xt4 = (const float4*)xt;
  const float4* __restrict__ ws4 = (const float4*)ws;
  for (int ks = 0; ks < 8; ++ks) {
    __syncthreads();
    {   // stage 128 rows x 16 k, transposed; 16B granule loads, L2-hot
      int grow = row0 + srow; if (grow > NN - 1) grow = NN - 1;
      const float* xp = x + (size_t)grow * 128 + ks * 16 + skh * 8;
      float4 va = *(const float4*)xp;
      float4 vb = *(const float4*)(xp + 4);
      const int kb = skh * 8;
      xt[(kb + 0) * 132 + srow] = va.x;
      xt[(kb + 1) * 132 + srow] = va.y;
      xt[(kb + 2) * 132 + srow] = va.z;
      xt[(kb + 3) * 132 + srow] = va.w;
      xt[(kb + 4) * 132 + srow] = vb.x;
      xt[(kb + 5) * 132 + srow] = vb.y;
      xt[(kb + 6) * 132 + srow] = vb.z;
      xt[(kb + 7) * 132 + srow] = vb.w;
    }
    __syncthreads();
    #pragma unroll 4
    for (int kk = 0; kk < 16; ++kk) {
      const int k = ks * 16 + kk;
      float4 xv = xt4[kk * 33 + rg];
      float4 wa = ws4[k * 16 + cg * 2];
      float4 wb = ws4[k * 16 + cg * 2 + 1];
      float xr[4] = {xv.x, xv.y, xv.z, xv.w};
      float wc[8] = {wa.x, wa.y, wa.z, wa.w, wb.x, wb.y, wb.z, wb.w};
      #pragma unroll
      for (int i = 0; i < 4; ++i)
        #pragma unroll
        for (int j = 0; j < 8; ++j)
          acc[i][j] = fmaf(xr[i], wc[j], acc[i][j]);
    }
  }
  #pragma unroll
  for (int i = 0; i < 4; ++i) {
    const int row = row0 + rg * 4 + i;
    if (row < NN) {
      uint4 o;
      o.x = pack2(acc[i][0], acc[i][1]);
      o.y = pack2(acc[i][2], acc[i][3]);
      o.z = pack2(acc[i][4], acc[i][5]);
      o.w = pack2(acc[i][6], acc[i][7]);
      ((uint4*)m1b)[row * 8 + cg] = o;   // ch 8cg..8cg+7
    }
  }
}

// ---------------- per-bucket LDS counting sort -> CSR + offsets + dinv ------
// seg0 computed in-block (scan of min(tail[0..b),BCAP), L2-hot) -- no
// separate prefix kernel. Epilogue: scale this bucket's 256 m1b rows in
// place by their dinv so agg1 gathers pre-scaled rows.

__global__ __launch_bounds__(256) void k_sort(const unsigned* __restrict__ bucket,
                                              const int* __restrict__ tail,
                                              int* __restrict__ csr_src,
                                              int* __restrict__ offsets,
                                              float* __restrict__ dinv,
                                              unsigned* __restrict__ m1b) {
  __shared__ int h[256], base_[256], loc[256];
  __shared__ float dv[256];
  __shared__ int sorted[BCAP];              // 34.8 KB
  __shared__ int wsum[4];
  __shared__ int seg0_s;
  const int b = blockIdx.x;
  const int lo = b << 8;
  const int nc = min(256, NN - lo);
  const int n = min(tail[b], BCAP);
  const unsigned* __restrict__ bk = bucket + (size_t)b * BCAP;
  const int tid = threadIdx.x, lane = tid & 63, wid = tid >> 6;
  h[tid] = 0; loc[tid] = 0;
  // ---- in-block exclusive prefix: seg0 = sum_{j<b} min(tail[j],BCAP) ----
  if (wid == 0) {
    int local = 0;
    const int lim = (b < NBUK) ? b : NBUK;     // sum over j < b
    for (int j = lane; j < lim; j += 64) local += min(tail[j], BCAP);
    #pragma unroll
    for (int d = 32; d > 0; d >>= 1) local += __shfl_xor(local, d, 64);
    if (lane == 0) seg0_s = local;
  }
  __syncthreads();
  const int seg0 = seg0_s;
  int i = tid * 4;
  for (; i + 3 < n; i += 1024) {
    uint4 v = *(const uint4*)(bk + i);
    atomicAdd(&h[v.x & 255u], 1);
    atomicAdd(&h[v.y & 255u], 1);
    atomicAdd(&h[v.z & 255u], 1);
    atomicAdd(&h[v.w & 255u], 1);
  }
  for (; i < n; ++i) atomicAdd(&h[bk[i] & 255u], 1);
  __syncthreads();
  {  // exclusive scan of h[0..255]
    int v = h[tid];
    int s = v;
    #pragma unroll
    for (int d = 1; d < 64; d <<= 1) { int t = __shfl_up(s, d, 64); if (lane >= d) s += t; }
    if (lane == 63) wsum[wid] = s;
    __syncthreads();
    int wpre = 0;
    #pragma unroll
    for (int w = 0; w < 4; ++w) if (w < wid) wpre += wsum[w];
    int excl = wpre + s - v;
    base_[tid] = excl;
    const float dval = rsqrtf((float)(v + 1));     // +1 = self-loop
    dv[tid] = dval;
    if (tid < nc) {
      dinv[lo + tid] = dval;
      offsets[lo + tid] = seg0 + excl;
    }
  }
  if (b == NBUK - 1 && tid == 0) offsets[NN] = seg0 + n;
  __syncthreads();
  i = tid * 4;
  for (; i + 3 < n; i += 1024) {
    uint4 v = *(const uint4*)(bk + i);
    { int c = v.x & 255u; sorted[base_[c] + atomicAdd(&loc[c], 1)] = (int)(v.x >> 8); }
    { int c = v.y & 255u; sorted[base_[c] + atomicAdd(&loc[c], 1)] = (int)(v.y >> 8); }
    { int c = v.z & 255u; sorted[base_[c] + atomicAdd(&loc[c], 1)] = (int)(v.z >> 8); }
    { int c = v.w & 255u; sorted[base_[c] + atomicAdd(&loc[c], 1)] = (int)(v.w >> 8); }
  }
  for (; i < n; ++i) {
    unsigned ent = bk[i];
    int c = ent & 255u;
    sorted[base_[c] + atomicAdd(&loc[c], 1)] = (int)(ent >> 8);
  }
  __syncthreads();
  for (int t = tid; t < n; t += 256) csr_src[seg0 + t] = sorted[t];   // coalesced
  // ---- scale m1b rows of this bucket's nodes (coalesced, 8 lanes/row) ----
  {
    const int q = tid & 7;
    uint4* __restrict__ m1rw = (uint4*)m1b;
    for (int r = tid >> 3; r < nc; r += 32) {
      const float d = dv[r];
      uint4 v = m1rw[(size_t)(lo + r) * 8 + q];
      v.x = pack2(__uint_as_float(v.x << 16) * d, __uint_as_float(v.x & 0xffff0000u) * d);
      v.y = pack2(__uint_as_float(v.y << 16) * d, __uint_as_float(v.y & 0xffff0000u) * d);
      v.z = pack2(__uint_as_float(v.z << 16) * d, __uint_as_float(v.z & 0xffff0000u) * d);
      v.w = pack2(__uint_as_float(v.w << 16) * d, __uint_as_float(v.w & 0xffff0000u) * d);
      m1rw[(size_t)(lo + r) * 8 + q] = v;
    }
  }
}

// ---------------- layer 1 aggregation (pre-scaled bf16 rows) ----------------
// Lane layout: e = lane>>3 (edge slot 0..7), q = lane&7 (16B chunk = 8 ch).
// Chunk = 32 edges via 4 dwordx4 gathers (8 rows each). Invalid slots clamp
// index to beg, weight 0. fp32 accumulate via v_pk_fma_f32.

__global__ __launch_bounds__(256) void k_agg1(const unsigned* __restrict__ m1b,
                                              const int* __restrict__ offsets,
                                              const int* __restrict__ csr_src,
                                              const float* __restrict__ dinv,
                                              const float* __restrict__ b1,
                                              float* __restrict__ a1) {
  const int node = blockIdx.x * 4 + (threadIdx.x >> 6);
  const int lane = threadIdx.x & 63;
  const int e = lane >> 3;
  const int q = lane & 7;
  const uint4* __restrict__ m1v = (const uint4*)m1b;
  const int beg = offsets[node], end = offsets[node + 1];
  f32x2 acc2[4];
  #pragma unroll
  for (int j = 0; j < 4; ++j) { acc2[j].x = 0.f; acc2[j].y = 0.f; }
  for (int p = beg; p < end; p += 32) {
    const int i0 = p + e, i1 = p + 8 + e, i2 = p + 16 + e, i3 = p + 24 + e;
    const int s0 = csr_src[i0 < end ? i0 : beg];
    const int s1 = csr_src[i1 < end ? i1 : beg];
    const int s2 = csr_src[i2 < end ? i2 : beg];
    const int s3 = csr_src[i3 < end ? i3 : beg];
    f32x2 f0; f0.x = f0.y = (i0 < end) ? 1.f : 0.f;
    f32x2 f1; f1.x = f1.y = (i1 < end) ? 1.f : 0.f;
    f32x2 f2; f2.x = f2.y = (i2 < end) ? 1.f : 0.f;
    f32x2 f3; f3.x = f3.y = (i3 < end) ? 1.f : 0.f;
    uint4 v0 = m1v[s0 * 8 + q];
    uint4 v1 = m1v[s1 * 8 + q];
    uint4 v2 = m1v[s2 * 8 + q];
    uint4 v3 = m1v[s3 * 8 + q];
    ACCP(v0, f0);
    ACCP(v1, f1);
    ACCP(v2, f2);
    ACCP(v3, f3);
  }
  float acc[8];
  acc[0] = acc2[0].x; acc[1] = acc2[0].y; acc[2] = acc2[1].x; acc[3] = acc2[1].y;
  acc[4] = acc2[2].x; acc[5] = acc2[2].y; acc[6] = acc2[3].x; acc[7] = acc2[3].y;
  // reduce the 8 edge slots; channel chunk q stays put
  #pragma unroll
  for (int j = 0; j < 8; ++j) {
    acc[j] += __shfl_xor(acc[j], 8, 64);
    acc[j] += __shfl_xor(acc[j], 16, 64);
    acc[j] += __shfl_xor(acc[j], 32, 64);
  }
  if (e == 0) {                       // lanes 0..7 hold chunk q = lane
    uint4 sv = m1v[node * 8 + q];     // self-loop row (pre-scaled)
    const float d = dinv[node];
    float4 bb0 = ((const float4*)b1)[q * 2];
    float4 bb1 = ((const float4*)b1)[q * 2 + 1];
    float4 o0, o1;
    o0.x = (acc[0] + __uint_as_float(sv.x << 16)) * d + bb0.x;
    o0.y = (acc[1] + __uint_as_float(sv.x & 0xffff0000u)) * d + bb0.y;
    o0.z = (acc[2] + __uint_as_float(sv.y << 16)) * d + bb0.z;
    o0.w = (acc[3] + __uint_as_float(sv.y & 0xffff0000u)) * d + bb0.w;
    o1.x = (acc[4] + __uint_as_float(sv.z << 16)) * d + bb1.x;
    o1.y = (acc[5] + __uint_as_float(sv.z & 0xffff0000u)) * d + bb1.y;
    o1.z = (acc[6] + __uint_as_float(sv.w << 16)) * d + bb1.z;
    o1.w = (acc[7] + __uint_as_float(sv.w & 0xffff0000u)) * d + bb1.w;
    ((float4*)a1)[node * 16 + q * 2] = o0;
    ((float4*)a1)[node * 16 + q * 2 + 1] = o1;
  }
}

// ---------------- layer 2 GEMM: m2b = bf16(dinv * (a1 @ W2)), 64 -> 40 ------

__global__ __launch_bounds__(256) void k_gemm2(const float* __restrict__ a1,
                                               const float* __restrict__ W2,
                                               const float* __restrict__ dinv,
                                               unsigned* __restrict__ m2b) {
  __shared__ float ws[64 * 40];    // 10 KB
  const int tid = threadIdx.x;
  for (int k = tid; k < 64 * 40; k += 256) ws[k] = W2[k];
  __syncthreads();
  const int idx = blockIdx.x * 256 + tid;                // thread = (node, ch-pair)
  if (idx >= NN * 20) return;
  const int node = idx / 20;
  const int c0 = (idx - node * 20) * 2;
  const float4* __restrict__ a4 = (const float4*)(a1 + node * 64);
  float acc0 = 0.f, acc1 = 0.f;
  #pragma unroll
  for (int k4 = 0; k4 < 16; ++k4) {
    float4 a = a4[k4];
    acc0 = fmaf(a.x, ws[(k4 * 4 + 0) * 40 + c0], acc0);
    acc1 = fmaf(a.x, ws[(k4 * 4 + 0) * 40 + c0 + 1], acc1);
    acc0 = fmaf(a.y, ws[(k4 * 4 + 1) * 40 + c0], acc0);
    acc1 = fmaf(a.y, ws[(k4 * 4 + 1) * 40 + c0 + 1], acc1);
    acc0 = fmaf(a.z, ws[(k4 * 4 + 2) * 40 + c0], acc0);
    acc1 = fmaf(a.z, ws[(k4 * 4 + 2) * 40 + c0 + 1], acc1);
    acc0 = fmaf(a.w, ws[(k4 * 4 + 3) * 40 + c0], acc0);
    acc1 = fmaf(a.w, ws[(k4 * 4 + 3) * 40 + c0 + 1], acc1);
  }
  const float d = dinv[node];
  m2b[idx] = pack2(acc0 * d, acc1 * d);
}

// ---------------- layer 2 aggregation + bias + log_softmax ------------------

__device__ __forceinline__ float shfl1(float v, int src) {
  return __shfl(v, src & 63, 64);
}

__global__ __launch_bounds__(256) void k_agg2(const unsigned* __restrict__ m2b,
                                              const int* __restrict__ offsets,
                                              const int* __restrict__ csr_src,
                                              const float* __restrict__ dinv,
                                              const float* __restrict__ b2,
                                              float* __restrict__ out) {
  const int node = blockIdx.x * 4 + (threadIdx.x >> 6);
  const int lane = threadIdx.x & 63;
  const bool act = lane < 60;
  const int e = act ? (lane / 5) : 0;
  const int q = act ? (lane - e * 5) : 0;
  const uint4* __restrict__ m2v = (const uint4*)m2b;
  const int beg = offsets[node], end = offsets[node + 1];
  f32x2 acc2[4];
  #pragma unroll
  for (int j = 0; j < 4; ++j) { acc2[j].x = 0.f; acc2[j].y = 0.f; }
  for (int p = beg; p < end; p += 48) {
    const int i0 = p + e, i1 = p + 12 + e, i2 = p + 24 + e, i3 = p + 36 + e;
    const int s0 = csr_src[i0 < end ? i0 : beg];
    const int s1 = csr_src[i1 < end ? i1 : beg];
    const int s2 = csr_src[i2 < end ? i2 : beg];
    const int s3 = csr_src[i3 < end ? i3 : beg];
    f32x2 f0; f0.x = f0.y = (act && i0 < end) ? 1.f : 0.f;
    f32x2 f1; f1.x = f1.y = (act && i1 < end) ? 1.f : 0.f;
    f32x2 f2; f2.x = f2.y = (act && i2 < end) ? 1.f : 0.f;
    f32x2 f3; f3.x = f3.y = (act && i3 < end) ? 1.f : 0.f;
    uint4 v0 = m2v[s0 * 5 + q];
    uint4 v1 = m2v[s1 * 5 + q];
    uint4 v2 = m2v[s2 * 5 + q];
    uint4 v3 = m2v[s3 * 5 + q];
    ACCP(v0, f0);
    ACCP(v1, f1);
    ACCP(v2, f2);
    ACCP(v3, f3);
  }
  float acc[8];
  acc[0] = acc2[0].x; acc[1] = acc2[0].y; acc[2] = acc2[1].x; acc[3] = acc2[1].y;
  acc[4] = acc2[2].x; acc[5] = acc2[2].y; acc[6] = acc2[3].x; acc[7] = acc2[3].y;
  // reduce 12 slots: +30, +15, then +5/+10 into lanes 0..4
  #pragma unroll
  for (int j = 0; j < 8; ++j) acc[j] += shfl1(acc[j], lane + 30);
  #pragma unroll
  for (int j = 0; j < 8; ++j) acc[j] += shfl1(acc[j], lane + 15);
  #pragma unroll
  for (int j = 0; j < 8; ++j) {
    float t1 = shfl1(acc[j], lane + 5);
    float t2 = shfl1(acc[j], lane + 10);
    acc[j] += t1 + t2;
  }
  const bool lead = (lane < 5);
  float r[8];
  #pragma unroll
  for (int j = 0; j < 8; ++j) r[j] = 0.f;
  if (lead) {
    uint4 sv = m2v[node * 5 + lane];   // self-loop row (q == lane here)
    const float d = dinv[node];
    float4 bb0 = ((const float4*)b2)[lane * 2];
    float4 bb1 = ((const float4*)b2)[lane * 2 + 1];
    r[0] = (acc[0] + __uint_as_float(sv.x << 16)) * d + bb0.x;
    r[1] = (acc[1] + __uint_as_float(sv.x & 0xffff0000u)) * d + bb0.y;
    r[2] = (acc[2] + __uint_as_float(sv.y << 16)) * d + bb0.z;
    r[3] = (acc[3] + __uint_as_float(sv.y & 0xffff0000u)) * d + bb0.w;
    r[4] = (acc[4] + __uint_as_float(sv.z << 16)) * d + bb1.x;
    r[5] = (acc[5] + __uint_as_float(sv.z & 0xffff0000u)) * d + bb1.y;
    r[6] = (acc[6] + __uint_as_float(sv.w << 16)) * d + bb1.z;
    r[7] = (acc[7] + __uint_as_float(sv.w & 0xffff0000u)) * d + bb1.w;
  }
  // log_softmax over 40 = 5 lanes x 8 comps (width-8 xor; lanes 5..7 seeded)
  float mx = -INFINITY;
  if (lead) {
    mx = fmaxf(fmaxf(fmaxf(r[0], r[1]), fmaxf(r[2], r[3])),
               fmaxf(fmaxf(r[4], r[5]), fmaxf(r[6], r[7])));
  }
  #pragma unroll
  for (int d = 4; d > 0; d >>= 1) mx = fmaxf(mx, __shfl_xor(mx, d, 8));
  float se = 0.f;
  if (lead) {
    se = __expf(r[0] - mx) + __expf(r[1] - mx) + __expf(r[2] - mx) +
         __expf(r[3] - mx) + __expf(r[4] - mx) + __expf(r[5] - mx) +
         __expf(r[6] - mx) + __expf(r[7] - mx);
  }
  #pragma unroll
  for (int d = 4; d > 0; d >>= 1) se += __shfl_xor(se, d, 8);
  if (lead) {
    const float lse = mx + logf(se);
    float4 o0, o1;
    o0.x = r[0] - lse; o0.y = r[1] - lse; o0.z = r[2] - lse; o0.w = r[3] - lse;
    o1.x = r[4] - lse; o1.y = r[5] - lse; o1.z = r[6] - lse; o1.w = r[7] - lse;
    ((float4*)out)[node * 10 + lane * 2] = o0;
    ((float4*)out)[node * 10 + lane * 2 + 1] = o1;
  }
}

// ---------------- launch ----------------

extern "C" void kernel_launch(void* const* d_in, const int* in_sizes, int n_in,
                              void* d_out, int out_size, void* d_ws, size_t ws_size,
                              hipStream_t stream) {
  const float* x   = (const float*)d_in[0];
  const int*   ei  = (const int*)d_in[1];   // [2][NE], int32
  const float* W1  = (const float*)d_in[3];
  const float* b1  = (const float*)d_in[4];
  const float* W2  = (const float*)d_in[5];
  const float* b2  = (const float*)d_in[6];
  float*       out = (float*)d_out;

  // workspace layout (liveness-checked):
  //   tail 0..1.6K | offsets 8K..0.4M | dinv 0.5M..0.9M
  //   csr_src 1.5M..14.3M
  //   m1b 14.5M..27.3M (fused gemm1 writes; concurrent with bucket;
  //                     scaled in place by k_sort epilogue)
  //   bucket 27.5M..40.5M (dead after k_sort)
  //   a1 27.5M..53.1M (overlays bucket; written by agg1 after sort)
  //   m2b = m1b (m1b dead after agg1)
  char* ws = (char*)d_ws;
  int*      tail    = (int*)(ws + 0);
  int*      offsets = (int*)(ws + (size_t)8 * 1024);
  float*    dinv    = (float*)(ws + (size_t)512 * 1024);
  int*      csr_src = (int*)(ws + (size_t)1536 * 1024);
  unsigned* m1b     = (unsigned*)(ws + (size_t)14848 * 1024);    // 14.5MB
  unsigned* bucket  = (unsigned*)(ws + (size_t)28160 * 1024);    // 27.5MB
  float*    a1      = (float*)(ws + (size_t)28160 * 1024);       // overlays bucket
  unsigned* m2b     = m1b;

  hipMemsetAsync(tail, 0, NBUK * 4, stream);
  k_bucket_gemm1<<<NBB + NGB, 256, 0, stream>>>(ei, tail, bucket, x, W1, m1b);
  k_sort<<<NBUK, 256, 0, stream>>>(bucket, tail, csr_src, offsets, dinv, m1b);
  k_agg1<<<NN / 4, 256, 0, stream>>>(m1b, offsets, csr_src, dinv, b1, a1);
  k_gemm2<<<(NN * 20 + 255) / 256, 256, 0, stream>>>(a1, W2, dinv, m2b);
  k_agg2<<<NN / 4, 256, 0, stream>>>(m2b, offsets, csr_src, dinv, b2, out);
}